// Round 1
// baseline (510.533 us; speedup 1.0000x reference)
//
#include <hip/hip_runtime.h>
#include <hip/hip_bf16.h>

// Problem constants (tiny-shakespeare bigram-ish transformer fwd)
#define VOCAB   65
#define NEMB    32
#define TBLK    8
#define NHEAD   4
#define HS      8
#define NB      131072

// ws layout (floats):
//   Qtab[8][65][32]  @ 0        (16640)
//   Ktab[8][65][32]  @ 16640
//   Vtab[8][65][32]  @ 33280
//   WlT [65][32]     @ 49920    (2080)
#define TABSZ   16640      // 8*65*32
#define WLT_OFF 49920      // 3*16640

// ---------------------------------------------------------------------------
// Kernel 1: build q/k/v tables over all (t, token) combos + transpose Wl.
// 52,000 outputs, 32 MACs each — trivial.
// ---------------------------------------------------------------------------
__global__ void build_tables(const float* __restrict__ tok_emb,
                             const float* __restrict__ pos_emb,
                             const float* __restrict__ Wq,
                             const float* __restrict__ Wk,
                             const float* __restrict__ Wv,
                             const float* __restrict__ Wl,
                             float* __restrict__ ws) {
    int e = blockIdx.x * blockDim.x + threadIdx.x;
    if (e < 3 * TABSZ) {
        int tab = e / TABSZ;
        int r   = e % TABSZ;
        int t   = r / (VOCAB * NEMB);
        int rem = r % (VOCAB * NEMB);
        int tok = rem / NEMB;
        int hd  = rem % NEMB;          // h*8 + d
        int h = hd >> 3, d = hd & 7;
        const float* W = (tab == 0) ? Wq : (tab == 1 ? Wk : Wv);
        float acc = 0.f;
        #pragma unroll
        for (int c = 0; c < NEMB; ++c) {
            float x = tok_emb[tok * NEMB + c] + pos_emb[t * NEMB + c];
            acc = fmaf(x, W[(h * NEMB + c) * HS + d], acc);
        }
        ws[tab * TABSZ + r] = acc;
    } else if (e < WLT_OFF + VOCAB * NEMB) {
        int i = e - WLT_OFF;
        int v = i >> 5, c = i & 31;
        ws[WLT_OFF + v * NEMB + c] = Wl[c * VOCAB + v];
    }
}

// ---------------------------------------------------------------------------
// Kernel 2: fused attention + FF + logits.
// One thread per (batch, t) row; 256 threads/block = 32 batches/block.
// ---------------------------------------------------------------------------
__global__ __launch_bounds__(256) void fused_lm(
        const int*   __restrict__ idx,
        const float* __restrict__ ws,
        const float* __restrict__ Wf,
        const float* __restrict__ bfv,
        const float* __restrict__ blv,
        float*       __restrict__ out) {

    __shared__ int   sidx[256];
    __shared__ float stage[256 * 16];   // logits staging tile (16 KB)

    const float* Qtab = ws;
    const float* Ktab = ws + TABSZ;
    const float* Vtab = ws + 2 * TABSZ;
    const float* WlT  = ws + WLT_OFF;

    const int tid = threadIdx.x;
    const int row0 = blockIdx.x * 256;          // first (b*8+t) row of block

    sidx[tid] = idx[row0 + tid];                // coalesced 256-int load
    __syncthreads();

    const int b_loc = tid >> 3;
    const int t     = tid & 7;

    // ---- gather q (32 floats, 128B-aligned row) ----
    const int tok_t = sidx[tid];
    float4 q[8];
    {
        const float4* qrow = (const float4*)(Qtab + (t * VOCAB + tok_t) * NEMB);
        #pragma unroll
        for (int i = 0; i < 8; ++i) q[i] = qrow[i];
    }

    // ---- pass 1: scores q.k for s<=t, all 4 heads ----
    const float scale = 0.17677669529663687f;   // 32^-0.5 (note: n_embed, not hs)
    float wei[4][8];
    #pragma unroll
    for (int s = 0; s < 8; ++s) {
        #pragma unroll
        for (int h = 0; h < 4; ++h) wei[h][s] = 0.f;
        if (s <= t) {
            int toks = sidx[(b_loc << 3) | s];
            const float4* krow = (const float4*)(Ktab + (s * VOCAB + toks) * NEMB);
            #pragma unroll
            for (int h = 0; h < 4; ++h) {
                float4 ka = krow[2 * h], kb = krow[2 * h + 1];
                float4 qa = q[2 * h],    qb = q[2 * h + 1];
                float d = qa.x * ka.x + qa.y * ka.y + qa.z * ka.z + qa.w * ka.w
                        + qb.x * kb.x + qb.y * kb.y + qb.z * kb.z + qb.w * kb.w;
                wei[h][s] = d * scale;
            }
        }
    }

    // ---- causal softmax per head (s in [0, t]) ----
    #pragma unroll
    for (int h = 0; h < 4; ++h) {
        float m = wei[h][0];
        #pragma unroll
        for (int s = 1; s < 8; ++s) if (s <= t) m = fmaxf(m, wei[h][s]);
        float sum = 0.f;
        #pragma unroll
        for (int s = 0; s < 8; ++s) {
            float e = (s <= t) ? __expf(wei[h][s] - m) : 0.f;
            wei[h][s] = e;
            sum += e;
        }
        float inv = 1.f / sum;
        #pragma unroll
        for (int s = 0; s < 8; ++s) wei[h][s] *= inv;
    }

    // ---- pass 2: out = P @ V (concat heads -> xatt[32]) ----
    float xatt[32];
    #pragma unroll
    for (int i = 0; i < 32; ++i) xatt[i] = 0.f;
    #pragma unroll
    for (int s = 0; s < 8; ++s) {
        if (s <= t) {
            int toks = sidx[(b_loc << 3) | s];
            const float4* vrow = (const float4*)(Vtab + (s * VOCAB + toks) * NEMB);
            #pragma unroll
            for (int h = 0; h < 4; ++h) {
                float4 va = vrow[2 * h], vb = vrow[2 * h + 1];
                float p = wei[h][s];
                xatt[h * 8 + 0] = fmaf(p, va.x, xatt[h * 8 + 0]);
                xatt[h * 8 + 1] = fmaf(p, va.y, xatt[h * 8 + 1]);
                xatt[h * 8 + 2] = fmaf(p, va.z, xatt[h * 8 + 2]);
                xatt[h * 8 + 3] = fmaf(p, va.w, xatt[h * 8 + 3]);
                xatt[h * 8 + 4] = fmaf(p, vb.x, xatt[h * 8 + 4]);
                xatt[h * 8 + 5] = fmaf(p, vb.y, xatt[h * 8 + 5]);
                xatt[h * 8 + 6] = fmaf(p, vb.z, xatt[h * 8 + 6]);
                xatt[h * 8 + 7] = fmaf(p, vb.w, xatt[h * 8 + 7]);
            }
        }
    }

    // ---- FeedForward: ff = relu(xatt @ Wf + bf); Wf reads are wave-uniform
    //      (scalar-cache s_load path), fmac with SGPR operand. ----
    float ff[32];
    #pragma unroll
    for (int j = 0; j < 32; ++j) ff[j] = bfv[j];
    #pragma unroll
    for (int c = 0; c < 32; ++c) {
        float xc = xatt[c];
        const float* wrow = Wf + c * NEMB;     // contiguous 128B, uniform
        #pragma unroll
        for (int j = 0; j < 32; ++j) ff[j] = fmaf(xc, wrow[j], ff[j]);
    }
    #pragma unroll
    for (int j = 0; j < 32; ++j) ff[j] = fmaxf(ff[j], 0.f);

    // ---- Logits: per-thread dot(ff, WlT[v]) for v-chunks of 16, staged
    //      through LDS so global stores are lane-contiguous (65-float rows
    //      are only 4B-aligned -> no direct float4 stores). ----
    const size_t blockBase = (size_t)blockIdx.x * (256 * VOCAB);
    #pragma unroll 1
    for (int cv = 0; cv < 4; ++cv) {
        const int v0 = cv * 16;
        #pragma unroll
        for (int vv = 0; vv < 16; ++vv) {
            const int v = v0 + vv;
            const float* wr = WlT + v * NEMB;  // uniform contiguous 128B
            float acc = blv[v];
            #pragma unroll
            for (int c = 0; c < 32; ++c) acc = fmaf(ff[c], wr[c], acc);
            stage[tid * 16 + vv] = acc;
        }
        __syncthreads();
        #pragma unroll
        for (int j = 0; j < 16; ++j) {
            int g = j * 256 + tid;             // lane-contiguous
            out[blockBase + (size_t)(g >> 4) * VOCAB + v0 + (g & 15)] = stage[g];
        }
        __syncthreads();
    }
    // v = 64 tail (direct scattered dword store, 1/65 of traffic)
    {
        const float* wr = WlT + 64 * NEMB;
        float acc = blv[64];
        #pragma unroll
        for (int c = 0; c < 32; ++c) acc = fmaf(ff[c], wr[c], acc);
        out[blockBase + (size_t)tid * VOCAB + 64] = acc;
    }
}

// ---------------------------------------------------------------------------
extern "C" void kernel_launch(void* const* d_in, const int* in_sizes, int n_in,
                              void* d_out, int out_size, void* d_ws, size_t ws_size,
                              hipStream_t stream) {
    const int*   idx     = (const int*)  d_in[0];
    const float* tok_emb = (const float*)d_in[1];
    const float* pos_emb = (const float*)d_in[2];
    const float* Wq      = (const float*)d_in[3];
    const float* Wk      = (const float*)d_in[4];
    const float* Wv      = (const float*)d_in[5];
    const float* Wf      = (const float*)d_in[6];
    const float* bf      = (const float*)d_in[7];
    const float* Wl      = (const float*)d_in[8];
    const float* bl      = (const float*)d_in[9];
    float* ws  = (float*)d_ws;
    float* out = (float*)d_out;

    // 52,000 table elements
    hipLaunchKernelGGL(build_tables, dim3(204), dim3(256), 0, stream,
                       tok_emb, pos_emb, Wq, Wk, Wv, Wl, ws);
    // 131072*8 rows / 256 threads = 4096 blocks
    hipLaunchKernelGGL(fused_lm, dim3(4096), dim3(256), 0, stream,
                       idx, ws, Wf, bf, bl, out);
}

// Round 2
// 506.591 us; speedup vs baseline: 1.0078x; 1.0078x over previous
//
#include <hip/hip_runtime.h>
#include <hip/hip_bf16.h>

// Problem constants (tiny-shakespeare bigram-ish transformer fwd)
#define VOCAB   65
#define NEMB    32
#define TBLK    8
#define NHEAD   4
#define HS      8
#define NB      131072

// ws layout (floats):
//   Qtab[8][65][32]  @ 0        (16640)
//   Ktab[8][65][32]  @ 16640
//   Vtab[8][65][32]  @ 33280
//   WlT [65][32]     @ 49920    (2080)
#define TABSZ   16640      // 8*65*32
#define WLT_OFF 49920      // 3*16640

// ---------------------------------------------------------------------------
// Kernel 1: build q/k/v tables over all (t, token) combos + transpose Wl.
// ---------------------------------------------------------------------------
__global__ void build_tables(const float* __restrict__ tok_emb,
                             const float* __restrict__ pos_emb,
                             const float* __restrict__ Wq,
                             const float* __restrict__ Wk,
                             const float* __restrict__ Wv,
                             const float* __restrict__ Wl,
                             float* __restrict__ ws) {
    int e = blockIdx.x * blockDim.x + threadIdx.x;
    if (e < 3 * TABSZ) {
        int tab = e / TABSZ;
        int r   = e % TABSZ;
        int t   = r / (VOCAB * NEMB);
        int rem = r % (VOCAB * NEMB);
        int tok = rem / NEMB;
        int hd  = rem % NEMB;          // h*8 + d
        int h = hd >> 3, d = hd & 7;
        const float* W = (tab == 0) ? Wq : (tab == 1 ? Wk : Wv);
        float acc = 0.f;
        #pragma unroll
        for (int c = 0; c < NEMB; ++c) {
            float x = tok_emb[tok * NEMB + c] + pos_emb[t * NEMB + c];
            acc = fmaf(x, W[(h * NEMB + c) * HS + d], acc);
        }
        ws[tab * TABSZ + r] = acc;
    } else if (e < WLT_OFF + VOCAB * NEMB) {
        int i = e - WLT_OFF;
        int v = i >> 5, c = i & 31;
        ws[WLT_OFF + v * NEMB + c] = Wl[c * VOCAB + v];
    }
}

// ---------------------------------------------------------------------------
// Kernel 2: fused attention + FF + logits.
// One thread per (batch, t) row; 256 threads/block = 32 batches/block.
// __launch_bounds__(256,3): VGPR cap ~170 so the ~110-float live set
// (q+wei, then xatt+ff) stays in registers — round-1 showed VGPR=72 with
// 6.2 GB of scratch-spill FETCH traffic.
// ---------------------------------------------------------------------------
__global__ __launch_bounds__(256, 3) void fused_lm(
        const int*   __restrict__ idx,
        const float* __restrict__ ws,
        const float* __restrict__ Wf,
        const float* __restrict__ bfv,
        const float* __restrict__ blv,
        float*       __restrict__ out) {

    __shared__ int   sidx[256];
    __shared__ float stage[256 * 16];   // logits staging tile (16 KB)

    const float* Qtab = ws;
    const float* Ktab = ws + TABSZ;
    const float* Vtab = ws + 2 * TABSZ;
    const float* WlT  = ws + WLT_OFF;

    const int tid = threadIdx.x;
    const int row0 = blockIdx.x * 256;          // first (b*8+t) row of block

    sidx[tid] = idx[row0 + tid];                // coalesced 256-int load
    __syncthreads();

    const int b_loc = tid >> 3;
    const int t     = tid & 7;

    // ---- gather q (32 floats, 128B-aligned row) ----
    const int tok_t = sidx[tid];
    float4 q[8];
    {
        const float4* qrow = (const float4*)(Qtab + (t * VOCAB + tok_t) * NEMB);
        #pragma unroll
        for (int i = 0; i < 8; ++i) q[i] = qrow[i];
    }

    // ---- pass 1: scores q.k, all s, all 4 heads (predicated, no branches) ----
    const float scale = 0.17677669529663687f;   // 32^-0.5 (n_embed, not hs)
    float wei[4][8];
    #pragma unroll
    for (int s = 0; s < 8; ++s) {
        const int toks = sidx[(b_loc << 3) | s];
        const float4* krow = (const float4*)(Ktab + (s * VOCAB + toks) * NEMB);
        const float mask = (s <= t) ? scale : -__builtin_inff();
        #pragma unroll
        for (int h = 0; h < 4; ++h) {
            float4 ka = krow[2 * h], kb = krow[2 * h + 1];
            float4 qa = q[2 * h],    qb = q[2 * h + 1];
            float d = qa.x * ka.x + qa.y * ka.y + qa.z * ka.z + qa.w * ka.w
                    + qb.x * kb.x + qb.y * kb.y + qb.z * kb.z + qb.w * kb.w;
            // s<=t: d*scale ; s>t: -inf (d finite, so d*(-inf) = +/-inf... )
            wei[h][s] = (s <= t) ? d * scale : -__builtin_inff();
            (void)mask;
        }
    }

    // ---- causal softmax per head (masked entries are -inf -> exp = 0) ----
    #pragma unroll
    for (int h = 0; h < 4; ++h) {
        float m = wei[h][0];
        #pragma unroll
        for (int s = 1; s < 8; ++s) m = fmaxf(m, wei[h][s]);
        float sum = 0.f;
        #pragma unroll
        for (int s = 0; s < 8; ++s) {
            float e = __expf(wei[h][s] - m);    // exp(-inf) = 0
            wei[h][s] = e;
            sum += e;
        }
        float inv = 1.f / sum;
        #pragma unroll
        for (int s = 0; s < 8; ++s) wei[h][s] *= inv;
    }

    // ---- pass 2: out = P @ V (concat heads -> xatt[32]), predicated p=0 ----
    float xatt[32];
    #pragma unroll
    for (int i = 0; i < 32; ++i) xatt[i] = 0.f;
    #pragma unroll
    for (int s = 0; s < 8; ++s) {
        const int toks = sidx[(b_loc << 3) | s];
        const float4* vrow = (const float4*)(Vtab + (s * VOCAB + toks) * NEMB);
        #pragma unroll
        for (int h = 0; h < 4; ++h) {
            float4 va = vrow[2 * h], vb = vrow[2 * h + 1];
            float p = wei[h][s];               // 0 for masked s (exp(-inf))
            xatt[h * 8 + 0] = fmaf(p, va.x, xatt[h * 8 + 0]);
            xatt[h * 8 + 1] = fmaf(p, va.y, xatt[h * 8 + 1]);
            xatt[h * 8 + 2] = fmaf(p, va.z, xatt[h * 8 + 2]);
            xatt[h * 8 + 3] = fmaf(p, va.w, xatt[h * 8 + 3]);
            xatt[h * 8 + 4] = fmaf(p, vb.x, xatt[h * 8 + 4]);
            xatt[h * 8 + 5] = fmaf(p, vb.y, xatt[h * 8 + 5]);
            xatt[h * 8 + 6] = fmaf(p, vb.z, xatt[h * 8 + 6]);
            xatt[h * 8 + 7] = fmaf(p, vb.w, xatt[h * 8 + 7]);
        }
    }

    // ---- FeedForward: ff = relu(xatt @ Wf + bf); wave-uniform weight reads
    //      (scalar-cache s_load path), fmac with SGPR operand. ----
    float ff[32];
    #pragma unroll
    for (int j = 0; j < 32; ++j) ff[j] = bfv[j];
    #pragma unroll
    for (int c = 0; c < 32; ++c) {
        float xc = xatt[c];
        const float* wrow = Wf + c * NEMB;     // contiguous 128B, uniform
        #pragma unroll
        for (int j = 0; j < 32; ++j) ff[j] = fmaf(xc, wrow[j], ff[j]);
    }
    #pragma unroll
    for (int j = 0; j < 32; ++j) ff[j] = fmaxf(ff[j], 0.f);

    // ---- Logits: per-thread dot(ff, WlT[v]) for v-chunks of 16, staged
    //      through LDS so global stores are lane-contiguous (65-float rows
    //      are only 4B-aligned -> no direct float4 stores). ----
    const size_t blockBase = (size_t)blockIdx.x * (256 * VOCAB);
    #pragma unroll 1
    for (int cv = 0; cv < 4; ++cv) {
        const int v0 = cv * 16;
        #pragma unroll
        for (int vv = 0; vv < 16; ++vv) {
            const int v = v0 + vv;
            const float* wr = WlT + v * NEMB;  // uniform contiguous 128B
            float acc = blv[v];
            #pragma unroll
            for (int c = 0; c < 32; ++c) acc = fmaf(ff[c], wr[c], acc);
            stage[tid * 16 + vv] = acc;
        }
        __syncthreads();
        #pragma unroll
        for (int j = 0; j < 16; ++j) {
            int g = j * 256 + tid;             // lane-contiguous
            out[blockBase + (size_t)(g >> 4) * VOCAB + v0 + (g & 15)] = stage[g];
        }
        __syncthreads();
    }
    // v = 64 tail (direct scattered dword store, 1/65 of traffic)
    {
        const float* wr = WlT + 64 * NEMB;
        float acc = blv[64];
        #pragma unroll
        for (int c = 0; c < 32; ++c) acc = fmaf(ff[c], wr[c], acc);
        out[blockBase + (size_t)tid * VOCAB + 64] = acc;
    }
}

// ---------------------------------------------------------------------------
extern "C" void kernel_launch(void* const* d_in, const int* in_sizes, int n_in,
                              void* d_out, int out_size, void* d_ws, size_t ws_size,
                              hipStream_t stream) {
    const int*   idx     = (const int*)  d_in[0];
    const float* tok_emb = (const float*)d_in[1];
    const float* pos_emb = (const float*)d_in[2];
    const float* Wq      = (const float*)d_in[3];
    const float* Wk      = (const float*)d_in[4];
    const float* Wv      = (const float*)d_in[5];
    const float* Wf      = (const float*)d_in[6];
    const float* bf      = (const float*)d_in[7];
    const float* Wl      = (const float*)d_in[8];
    const float* bl      = (const float*)d_in[9];
    float* ws  = (float*)d_ws;
    float* out = (float*)d_out;

    // 52,000 table elements
    hipLaunchKernelGGL(build_tables, dim3(204), dim3(256), 0, stream,
                       tok_emb, pos_emb, Wq, Wk, Wv, Wl, ws);
    // 131072*8 rows / 256 threads = 4096 blocks
    hipLaunchKernelGGL(fused_lm, dim3(4096), dim3(256), 0, stream,
                       idx, ws, Wf, bf, bl, out);
}